// Round 6
// baseline (1537.993 us; speedup 1.0000x reference)
//
#include <hip/hip_runtime.h>
#include <stdint.h>
#include <stddef.h>

// W4A8 fake-quant SwiGLU MLP for MI355X (gfx950).
// Exact-integer reformulation: fake-quant values are int*scale, so every
// matmul is an int8 x int4 integer GEMM (exact in i32/f32) times rank-1 scales.
//
// R1: gemm1 launch-bounds spill fix (2700 -> 527 us).
// R2: XCD swizzle (527 -> 499). R3: gemm2 128x256; merged quant launches.
// R4: 2-phase dbuf w/ __syncthreads REGRESSED (vmcnt(0) drain; m99/m233).
// R5: coarse counted-vmcnt pipeline NULL (m196: coarse split w/o fine
//     interleave doesn't pay). Kept fused h-absmax + single-pass quant_h.
// R6: 8-phase 256^2 schedule (m201 template) for BOTH GEMMs:
//     512 thr / 8 waves (2Mx4N), per-wave 128x64 out, acc[8][4]=128 VGPR,
//     3 LDS buffers (96 KB) depth-2 prefetch, per-phase
//     {ds_read || 1 gl2lds} -> barrier -> lgkmcnt(0) -> 8 MFMA -> barrier,
//     vmcnt(4) only at tile boundary (never drains mid-loop).
//     gemm1 is a SINGLE GEMM over row-interleaved Wcat[2F,D] (Wg->2j,
//     Wu->2j+1); epilogue pairs (g,u) via shfl_xor(1) -> silu fusion exact.

using i32x4 = __attribute__((ext_vector_type(4))) int;

#define BK 64
#define BT 256   // tile edge (M and N)

__device__ __forceinline__ void gl2lds16(const void* gptr, void* lptr) {
  __builtin_amdgcn_global_load_lds(
      (const __attribute__((address_space(1))) uint32_t*)gptr,
      (__attribute__((address_space(3))) uint32_t*)lptr, 16, 0, 0);
}

// ---------------------------------------------------------------------------
// Merged per-row fake-quant for x, Wg, Wu, Wd in ONE launch.
// Wg row j -> wcat row 2j ; Wu row j -> wcat row 2j+1 (pair-interleaved).
// Also zero-inits hmax[row] in the x segment.
// ---------------------------------------------------------------------------
__global__ void quant_all_kernel(
    const float* __restrict__ x, const float* __restrict__ Wg,
    const float* __restrict__ Wu, const float* __restrict__ Wd,
    int8_t* __restrict__ xq, int8_t* __restrict__ wcat,
    int8_t* __restrict__ wdq,
    float* __restrict__ sx, float* __restrict__ swg,
    float* __restrict__ swu, float* __restrict__ swd,
    int* __restrict__ hmax) {
  const int b = blockIdx.x;
  const float* src;
  int8_t* dst;
  float* scp;
  int cols;
  float qmax, qmin;
  if (b < 4096) {
    src = x + (size_t)b * 4096; dst = xq + (size_t)b * 4096;
    scp = sx + b; cols = 4096; qmax = 127.0f; qmin = -128.0f;
    if (threadIdx.x == 0) hmax[b] = 0;
  } else if (b < 4096 + 11008) {
    const int j = b - 4096;
    src = Wg + (size_t)j * 4096; dst = wcat + (size_t)(2 * j) * 4096;
    scp = swg + j; cols = 4096; qmax = 7.0f; qmin = -8.0f;
  } else if (b < 4096 + 22016) {
    const int j = b - 15104;
    src = Wu + (size_t)j * 4096; dst = wcat + (size_t)(2 * j + 1) * 4096;
    scp = swu + j; cols = 4096; qmax = 7.0f; qmin = -8.0f;
  } else {
    const int j = b - 26112;
    src = Wd + (size_t)j * 11008; dst = wdq + (size_t)j * 11008;
    scp = swd + j; cols = 11008; qmax = 7.0f; qmin = -8.0f;
  }
  const int n4 = cols >> 2;
  const float4* s4 = (const float4*)src;
  float amax = 0.0f;
  for (int i = threadIdx.x; i < n4; i += blockDim.x) {
    float4 v = s4[i];
    amax = fmaxf(amax, fmaxf(fmaxf(fabsf(v.x), fabsf(v.y)),
                             fmaxf(fabsf(v.z), fabsf(v.w))));
  }
#pragma unroll
  for (int off = 32; off > 0; off >>= 1)
    amax = fmaxf(amax, __shfl_xor(amax, off, 64));
  __shared__ float wmax[4];
  if ((threadIdx.x & 63) == 0) wmax[threadIdx.x >> 6] = amax;
  __syncthreads();
  const float scale =
      fmaxf(fmaxf(fmaxf(wmax[0], wmax[1]), fmaxf(wmax[2], wmax[3])) / qmax,
            1e-8f);
  if (threadIdx.x == 0) *scp = scale;
  char4* d4 = (char4*)dst;
  for (int i = threadIdx.x; i < n4; i += blockDim.x) {
    float4 v = s4[i];
    char4 q;
    q.x = (char)(int)fminf(fmaxf(rintf(v.x / scale), qmin), qmax);
    q.y = (char)(int)fminf(fmaxf(rintf(v.y / scale), qmin), qmax);
    q.z = (char)(int)fminf(fmaxf(rintf(v.z / scale), qmin), qmax);
    q.w = (char)(int)fminf(fmaxf(rintf(v.w / scale), qmin), qmax);
    d4[i] = q;
  }
}

// Single-pass per-row quant of h: absmax comes from gemm1's fused atomicMax.
__global__ void quant_h_kernel(const float* __restrict__ h,
                               int8_t* __restrict__ hq,
                               float* __restrict__ sh,
                               const int* __restrict__ hmax, int cols) {
  const int row = blockIdx.x;
  const float amax = __int_as_float(hmax[row]);
  const float scale = fmaxf(amax / 127.0f, 1e-8f);
  if (threadIdx.x == 0) sh[row] = scale;
  const int n4 = cols >> 2;
  const float4* s4 = (const float4*)(h + (size_t)row * cols);
  char4* d4 = (char4*)(hq + (size_t)row * cols);
  for (int i = threadIdx.x; i < n4; i += blockDim.x) {
    float4 v = s4[i];
    char4 q;
    q.x = (char)(int)fminf(fmaxf(rintf(v.x / scale), -128.0f), 127.0f);
    q.y = (char)(int)fminf(fmaxf(rintf(v.y / scale), -128.0f), 127.0f);
    q.z = (char)(int)fminf(fmaxf(rintf(v.z / scale), -128.0f), 127.0f);
    q.w = (char)(int)fminf(fmaxf(rintf(v.w / scale), -128.0f), 127.0f);
    d4[i] = q;
  }
}

// Bijective XCD-aware remap of the linear block id (requires nwg % 8 == 0).
__device__ __forceinline__ int xcd_swizzle(int lid, int nwg) {
  const int cpx = nwg >> 3;
  return (lid & 7) * cpx + (lid >> 3);
}

// --- shared 8-phase machinery -----------------------------------------------
// Staging: 256x64 i8 tile = 1024 16B chunks; 512 threads x 2 halves.
// Chunk c: row r=c>>2, LDS slot s=c&3; XOR-swizzled source k-chunk
// kc=((s-(r>>1))&3)<<4; read of frag row ar at k-quad q uses slot (q+(ar>>1))&3.
#define STG(mat, base_row, buf, kt, half)                                     \
  {                                                                           \
    const int c = tid + (half)*512;                                           \
    const int r = c >> 2;                                                     \
    const int s = c & 3;                                                      \
    const int kc = ((s - (r >> 1)) & 3) << 4;                                 \
    gl2lds16(mat + (size_t)((base_row) + r) * K + ((kt)*BK + kc),             \
             buf + c * 16);                                                   \
  }

#define PHSYNC()                                                              \
  __builtin_amdgcn_s_barrier();                                               \
  asm volatile("s_waitcnt lgkmcnt(0)" ::: "memory");                          \
  __builtin_amdgcn_sched_barrier(0);

#define LDA2(i0)                                                              \
  {                                                                           \
    const int ar0 = wm * 128 + (i0)*16 + l16;                                 \
    af0 = *(const i32x4*)(sAc + ar0 * BK + (((quad + (ar0 >> 1)) & 3) << 4)); \
    const int ar1 = wm * 128 + ((i0) + 1) * 16 + l16;                         \
    af1 = *(const i32x4*)(sAc + ar1 * BK + (((quad + (ar1 >> 1)) & 3) << 4)); \
  }

#define MMA2(i0)                                                              \
  _Pragma("unroll") for (int j = 0; j < 4; ++j) {                             \
    acc[i0][j] =                                                              \
        __builtin_amdgcn_mfma_i32_16x16x64_i8(af0, bf[j], acc[i0][j], 0, 0, 0); \
    acc[(i0) + 1][j] = __builtin_amdgcn_mfma_i32_16x16x64_i8(                 \
        af1, bf[j], acc[(i0) + 1][j], 0, 0, 0);                               \
  }

// Main-loop body shared by both GEMMs (A in sA[], B in sB[], srcA/srcB ptrs).
#define KLOOP(srcA, srcB)                                                     \
  for (int t = 0; t < T; ++t) {                                               \
    const int cur = t % 3;                                                    \
    const int nb = (t + 2) % 3;                                               \
    const bool pf = (t + 2) < T;                                              \
    const int8_t* sAc = sA[cur];                                              \
    const int8_t* sBc = sB[cur];                                              \
    i32x4 bf[4];                                                              \
    i32x4 af0, af1;                                                           \
    /* phase 0: B frags + A 0-1 */                                            \
    _Pragma("unroll") for (int j = 0; j < 4; ++j) {                           \
      const int br = wn * 64 + j * 16 + l16;                                  \
      bf[j] =                                                                 \
          *(const i32x4*)(sBc + br * BK + (((quad + (br >> 1)) & 3) << 4));   \
    }                                                                         \
    LDA2(0);                                                                  \
    if (pf) STG(srcA, m0, sA[nb], t + 2, 0);                                  \
    PHSYNC();                                                                 \
    __builtin_amdgcn_s_setprio(1);                                            \
    MMA2(0);                                                                  \
    __builtin_amdgcn_s_setprio(0);                                            \
    __builtin_amdgcn_s_barrier();                                             \
    /* phase 1 */                                                             \
    LDA2(2);                                                                  \
    if (pf) STG(srcA, m0, sA[nb], t + 2, 1);                                  \
    PHSYNC();                                                                 \
    __builtin_amdgcn_s_setprio(1);                                            \
    MMA2(2);                                                                  \
    __builtin_amdgcn_s_setprio(0);                                            \
    __builtin_amdgcn_s_barrier();                                             \
    /* phase 2 */                                                             \
    LDA2(4);                                                                  \
    if (pf) STG(srcB, n0, sB[nb], t + 2, 0);                                  \
    PHSYNC();                                                                 \
    __builtin_amdgcn_s_setprio(1);                                            \
    MMA2(4);                                                                  \
    __builtin_amdgcn_s_setprio(0);                                            \
    __builtin_amdgcn_s_barrier();                                             \
    /* phase 3 */                                                             \
    LDA2(6);                                                                  \
    if (pf) STG(srcB, n0, sB[nb], t + 2, 1);                                  \
    PHSYNC();                                                                 \
    __builtin_amdgcn_s_setprio(1);                                            \
    MMA2(6);                                                                  \
    __builtin_amdgcn_s_setprio(0);                                            \
    /* tile boundary: next tile's loads done, keep depth-2 in flight */       \
    if (pf)                                                                   \
      asm volatile("s_waitcnt vmcnt(4)" ::: "memory");                        \
    else                                                                      \
      asm volatile("s_waitcnt vmcnt(0)" ::: "memory");                        \
    __builtin_amdgcn_s_barrier();                                             \
  }

// Fused gate+up GEMM over pair-interleaved Wcat: C = xq @ wcat^T (i32),
// epilogue pairs adjacent lanes (even=gate, odd=up), h = silu(g)*u -> hbuf,
// per-row |h| max -> atomicMax(hmax[row]).
__global__ __launch_bounds__(512, 2) void gemm1_kernel(
    const int8_t* __restrict__ xq, const int8_t* __restrict__ wcq,
    const float* __restrict__ sx, const float* __restrict__ swg,
    const float* __restrict__ swu, float* __restrict__ hbuf,
    int* __restrict__ hmax, int M, int Ncat, int K, int F) {
  __shared__ __align__(16) int8_t sA[3][BT * BK];  // 3 x 16 KB
  __shared__ __align__(16) int8_t sB[3][BT * BK];  // 3 x 16 KB

  const int tid = threadIdx.x;
  const int lane = tid & 63;
  const int quad = lane >> 4;
  const int l16 = lane & 15;
  const int wave = tid >> 6;
  const int wm = wave >> 2;  // 0..1 : 128-row group
  const int wn = wave & 3;   // 0..3 : 64-col group

  const int nwg = gridDim.x * gridDim.y;
  const int lid = xcd_swizzle(blockIdx.y * gridDim.x + blockIdx.x, nwg);
  const int n0 = (lid % gridDim.x) * BT;
  const int m0 = (lid / gridDim.x) * BT;

  const int T = K / BK;

  i32x4 acc[8][4] = {};

  // prologue: tiles 0 and 1 (4 loads each)
  STG(xq, m0, sA[0], 0, 0); STG(xq, m0, sA[0], 0, 1);
  STG(wcq, n0, sB[0], 0, 0); STG(wcq, n0, sB[0], 0, 1);
  STG(xq, m0, sA[1], 1, 0); STG(xq, m0, sA[1], 1, 1);
  STG(wcq, n0, sB[1], 1, 0); STG(wcq, n0, sB[1], 1, 1);
  asm volatile("s_waitcnt vmcnt(4)" ::: "memory");
  __builtin_amdgcn_s_barrier();

  KLOOP(xq, wcq);

  // epilogue: pair (g,u) via shfl_xor(1); even lanes write h.
  float sc[4];
#pragma unroll
  for (int j = 0; j < 4; ++j) {
    const int c = n0 + wn * 64 + j * 16 + l16;
    sc[j] = (c & 1) ? swu[c >> 1] : swg[c >> 1];
  }
#pragma unroll
  for (int i = 0; i < 8; ++i) {
#pragma unroll
    for (int r = 0; r < 4; ++r) {
      const int row = m0 + wm * 128 + i * 16 + quad * 4 + r;
      const float s_x = sx[row];
      float rmax = 0.0f;
#pragma unroll
      for (int j = 0; j < 4; ++j) {
        const float vs = (float)acc[i][j][r] * s_x * sc[j];
        const float pv = __shfl_xor(vs, 1, 64);
        const float g = (l16 & 1) ? pv : vs;
        const float u = (l16 & 1) ? vs : pv;
        const float hv = (g / (1.0f + expf(-g))) * u;  // silu(g)*u
        if (!(l16 & 1)) {
          const int hcol = (n0 >> 1) + wn * 32 + j * 8 + (l16 >> 1);
          hbuf[(size_t)row * F + hcol] = hv;
        }
        rmax = fmaxf(rmax, fabsf(hv));
      }
#pragma unroll
      for (int off = 8; off > 0; off >>= 1)
        rmax = fmaxf(rmax, __shfl_xor(rmax, off, 64));
      if (l16 == 0)
        atomicMax(hmax + row, __float_as_int(rmax));  // nonneg f32: int-mono
    }
  }
}

// Down-projection GEMM: out = (hq @ Wd^T) * sh[m] * swd[n], same template.
__global__ __launch_bounds__(512, 2) void gemm2_kernel(
    const int8_t* __restrict__ hq, const int8_t* __restrict__ wdq,
    const float* __restrict__ sh, const float* __restrict__ swd,
    float* __restrict__ out, int M, int N, int K) {
  __shared__ __align__(16) int8_t sA[3][BT * BK];
  __shared__ __align__(16) int8_t sB[3][BT * BK];

  const int tid = threadIdx.x;
  const int lane = tid & 63;
  const int quad = lane >> 4;
  const int l16 = lane & 15;
  const int wave = tid >> 6;
  const int wm = wave >> 2;
  const int wn = wave & 3;

  const int nwg = gridDim.x * gridDim.y;
  const int lid = xcd_swizzle(blockIdx.y * gridDim.x + blockIdx.x, nwg);
  const int n0 = (lid % gridDim.x) * BT;
  const int m0 = (lid / gridDim.x) * BT;

  const int T = K / BK;  // 172

  i32x4 acc[8][4] = {};

  STG(hq, m0, sA[0], 0, 0); STG(hq, m0, sA[0], 0, 1);
  STG(wdq, n0, sB[0], 0, 0); STG(wdq, n0, sB[0], 0, 1);
  STG(hq, m0, sA[1], 1, 0); STG(hq, m0, sA[1], 1, 1);
  STG(wdq, n0, sB[1], 1, 0); STG(wdq, n0, sB[1], 1, 1);
  asm volatile("s_waitcnt vmcnt(4)" ::: "memory");
  __builtin_amdgcn_s_barrier();

  KLOOP(hq, wdq);

  float sn[4];
#pragma unroll
  for (int j = 0; j < 4; ++j) sn[j] = swd[n0 + wn * 64 + j * 16 + l16];
#pragma unroll
  for (int i = 0; i < 8; ++i) {
#pragma unroll
    for (int r = 0; r < 4; ++r) {
      const int row = m0 + wm * 128 + i * 16 + quad * 4 + r;
      const float s_m = sh[row];
#pragma unroll
      for (int j = 0; j < 4; ++j) {
        const int col = n0 + wn * 64 + j * 16 + l16;
        out[(size_t)row * N + col] = (float)acc[i][j][r] * s_m * sn[j];
      }
    }
  }
}

extern "C" void kernel_launch(void* const* d_in, const int* in_sizes, int n_in,
                              void* d_out, int out_size, void* d_ws, size_t ws_size,
                              hipStream_t stream) {
  const float* x  = (const float*)d_in[0];   // [2,2048,4096]
  const float* Wg = (const float*)d_in[1];   // [11008,4096]
  const float* Wu = (const float*)d_in[2];   // [11008,4096]
  const float* Wd = (const float*)d_in[3];   // [4096,11008]
  float* out = (float*)d_out;                // [2,2048,4096] f32

  const int M = 4096;   // B*S
  const int D = 4096;
  const int F = 11008;
  const int Ncat = 2 * F;  // 22016

  // workspace layout (~378 MB total), all offsets 16B-aligned
  uint8_t* ws = (uint8_t*)d_ws;
  size_t off = 0;
  int8_t* xq   = (int8_t*)(ws + off); off += (size_t)M * D;        // 16 MB
  int8_t* wcat = (int8_t*)(ws + off); off += (size_t)Ncat * D;     // 90 MB
  int8_t* wdq  = (int8_t*)(ws + off); off += (size_t)D * F;        // 45 MB
  int8_t* hq   = (int8_t*)(ws + off); off += (size_t)M * F;        // 45 MB
  float* hbuf  = (float*)(ws + off);  off += (size_t)M * F * 4;    // 180 MB
  float* sx    = (float*)(ws + off);  off += (size_t)M * 4;
  float* swg   = (float*)(ws + off);  off += (size_t)F * 4;
  float* swu   = (float*)(ws + off);  off += (size_t)F * 4;
  float* swd   = (float*)(ws + off);  off += (size_t)D * 4;
  float* sh    = (float*)(ws + off);  off += (size_t)M * 4;
  int*   hmax  = (int*)(ws + off);    off += (size_t)M * 4;

  hipLaunchKernelGGL(quant_all_kernel, dim3(M + F + F + D), dim3(256), 0,
                     stream, x, Wg, Wu, Wd, xq, wcat, wdq,
                     sx, swg, swu, swd, hmax);
  hipLaunchKernelGGL(gemm1_kernel, dim3(Ncat / BT, M / BT), dim3(512), 0,
                     stream, xq, wcat, sx, swg, swu, hbuf, hmax, M, Ncat, D, F);
  hipLaunchKernelGGL(quant_h_kernel, dim3(M), dim3(256), 0, stream,
                     hbuf, hq, sh, hmax, F);
  hipLaunchKernelGGL(gemm2_kernel, dim3(D / BT, M / BT), dim3(512), 0, stream,
                     hq, wdq, sh, swd, out, M, D, F);
}

// Round 7
// 1343.665 us; speedup vs baseline: 1.1446x; 1.1446x over previous
//
#include <hip/hip_runtime.h>
#include <stdint.h>
#include <stddef.h>

// W4A8 fake-quant SwiGLU MLP for MI355X (gfx950).
// Exact-integer reformulation: fake-quant values are int*scale, so every
// matmul is an int8 x int4 integer GEMM (exact in i32/f32) times rank-1 scales.
// GEMMs: mfma_i32_16x16x64_i8, global_load_lds width-16,
// XOR-swizzled LDS (slot = (quad + (row>>1)) & 3) for conflict-free b128 reads.
//
// R1: gemm1 launch-bounds spill fix (2700 -> 527 us).
// R2: XCD swizzle (527 -> 499). R3: gemm2 128x256; merged quant launches.
// R4: 2-phase dbuf w/ __syncthreads REGRESSED (vmcnt(0) drain; m99/m233).
// R5: coarse counted-vmcnt pipeline NULL. R6: 8-phase i8 port REGRESSED
//     (8-MFMA clusters between 2 barriers + 1 block/CU: phase overhead
//     dominates) -- but its 256^2 tile showed FETCH 1.44 -> 0.73 GB.
// R7: revert to R2/R3 GEMM structures; fix rasterization to M-MAJOR:
//     consecutive block ids sweep m-tiles within a narrow n-panel group, so
//     a concurrent generation touches ~16 MB of weights instead of all 90 MB
//     -> HBM fetch should approach the cold-miss floor. Keeps merged
//     quant_all, fused h-absmax (atomicMax), single-pass quant_h.

using i32x4 = __attribute__((ext_vector_type(4))) int;

#define BM 128
#define BN 128
#define BN2 256
#define BK 64

__device__ __forceinline__ void gl2lds16(const void* gptr, void* lptr) {
  __builtin_amdgcn_global_load_lds(
      (const __attribute__((address_space(1))) uint32_t*)gptr,
      (__attribute__((address_space(3))) uint32_t*)lptr, 16, 0, 0);
}

// ---------------------------------------------------------------------------
// Merged per-row symmetric fake-quant for all four inputs in ONE launch.
// blockIdx segments: [0,4096) x | [4096,15104) Wg | [15104,26112) Wu |
// [26112,30208) Wd. Also zero-inits hmax[row] in the x segment.
// ---------------------------------------------------------------------------
__global__ void quant_all_kernel(
    const float* __restrict__ x, const float* __restrict__ Wg,
    const float* __restrict__ Wu, const float* __restrict__ Wd,
    int8_t* __restrict__ xq, int8_t* __restrict__ wgq,
    int8_t* __restrict__ wuq, int8_t* __restrict__ wdq,
    float* __restrict__ sx, float* __restrict__ swg,
    float* __restrict__ swu, float* __restrict__ swd,
    int* __restrict__ hmax) {
  const int b = blockIdx.x;
  const float* src;
  int8_t* dst;
  float* scales;
  int cols, row;
  float qmax, qmin;
  if (b < 4096) {
    src = x; dst = xq; scales = sx; cols = 4096; row = b;
    qmax = 127.0f; qmin = -128.0f;
    if (threadIdx.x == 0) hmax[row] = 0;  // init for gemm1's atomicMax
  } else if (b < 4096 + 11008) {
    src = Wg; dst = wgq; scales = swg; cols = 4096; row = b - 4096;
    qmax = 7.0f; qmin = -8.0f;
  } else if (b < 4096 + 22016) {
    src = Wu; dst = wuq; scales = swu; cols = 4096; row = b - 15104;
    qmax = 7.0f; qmin = -8.0f;
  } else {
    src = Wd; dst = wdq; scales = swd; cols = 11008; row = b - 26112;
    qmax = 7.0f; qmin = -8.0f;
  }
  const int n4 = cols >> 2;
  const float4* s4 = (const float4*)(src + (size_t)row * cols);
  float amax = 0.0f;
  for (int i = threadIdx.x; i < n4; i += blockDim.x) {
    float4 v = s4[i];
    amax = fmaxf(amax, fmaxf(fmaxf(fabsf(v.x), fabsf(v.y)),
                             fmaxf(fabsf(v.z), fabsf(v.w))));
  }
#pragma unroll
  for (int off = 32; off > 0; off >>= 1)
    amax = fmaxf(amax, __shfl_xor(amax, off, 64));
  __shared__ float wmax[4];
  if ((threadIdx.x & 63) == 0) wmax[threadIdx.x >> 6] = amax;
  __syncthreads();
  const float scale =
      fmaxf(fmaxf(fmaxf(wmax[0], wmax[1]), fmaxf(wmax[2], wmax[3])) / qmax,
            1e-8f);
  if (threadIdx.x == 0) scales[row] = scale;
  char4* d4 = (char4*)(dst + (size_t)row * cols);
  for (int i = threadIdx.x; i < n4; i += blockDim.x) {
    float4 v = s4[i];
    char4 q;
    q.x = (char)(int)fminf(fmaxf(rintf(v.x / scale), qmin), qmax);
    q.y = (char)(int)fminf(fmaxf(rintf(v.y / scale), qmin), qmax);
    q.z = (char)(int)fminf(fmaxf(rintf(v.z / scale), qmin), qmax);
    q.w = (char)(int)fminf(fmaxf(rintf(v.w / scale), qmin), qmax);
    d4[i] = q;
  }
}

// Single-pass per-row quant of h: absmax comes from gemm1's fused atomicMax.
__global__ void quant_h_kernel(const float* __restrict__ h,
                               int8_t* __restrict__ hq,
                               float* __restrict__ sh,
                               const int* __restrict__ hmax, int cols) {
  const int row = blockIdx.x;
  const float amax = __int_as_float(hmax[row]);
  const float scale = fmaxf(amax / 127.0f, 1e-8f);
  if (threadIdx.x == 0) sh[row] = scale;
  const int n4 = cols >> 2;
  const float4* s4 = (const float4*)(h + (size_t)row * cols);
  char4* d4 = (char4*)(hq + (size_t)row * cols);
  for (int i = threadIdx.x; i < n4; i += blockDim.x) {
    float4 v = s4[i];
    char4 q;
    q.x = (char)(int)fminf(fmaxf(rintf(v.x / scale), -128.0f), 127.0f);
    q.y = (char)(int)fminf(fmaxf(rintf(v.y / scale), -128.0f), 127.0f);
    q.z = (char)(int)fminf(fmaxf(rintf(v.z / scale), -128.0f), 127.0f);
    q.w = (char)(int)fminf(fmaxf(rintf(v.w / scale), -128.0f), 127.0f);
    d4[i] = q;
  }
}

// Bijective XCD-aware remap of the linear block id (requires nwg % 8 == 0).
__device__ __forceinline__ int xcd_swizzle(int lid, int nwg) {
  const int cpx = nwg >> 3;
  return (lid & 7) * cpx + (lid >> 3);
}

// Fused gate+up GEMM: acc_g = xq @ Wg^T, acc_u = xq @ Wu^T (int32 exact),
// epilogue h = silu(acc_g*sx*swg) * (acc_u*sx*swu) -> hbuf (f32),
// plus per-row |h| max -> atomicMax(hmax[row]).
// M-MAJOR raster: consecutive lids sweep m-tiles within one n-panel.
__global__ __launch_bounds__(256, 2) void gemm1_kernel(
    const int8_t* __restrict__ xq, const int8_t* __restrict__ wgq,
    const int8_t* __restrict__ wuq, const float* __restrict__ sx,
    const float* __restrict__ swg, const float* __restrict__ swu,
    float* __restrict__ hbuf, int* __restrict__ hmax, int M, int N, int K) {
  __shared__ __align__(16) int8_t sA[BM * BK];
  __shared__ __align__(16) int8_t sBg[BN * BK];
  __shared__ __align__(16) int8_t sBu[BN * BK];

  const int tid = threadIdx.x;
  const int lane = tid & 63;
  const int quad = lane >> 4;
  const int l16 = lane & 15;
  const int wave = tid >> 6;
  const int wm = wave >> 1;
  const int wn = wave & 1;

  const int nwg = gridDim.x * gridDim.y;
  const int lid = xcd_swizzle(blockIdx.y * gridDim.x + blockIdx.x, nwg);
  const int nm = gridDim.y;                 // # of m-tiles (32)
  const int m0 = (lid % nm) * BM;           // m-major: m varies fastest
  const int n0 = (lid / nm) * BN;

  i32x4 accg[4][4] = {};
  i32x4 accu[4][4] = {};

  for (int k0 = 0; k0 < K; k0 += BK) {
#pragma unroll
    for (int it = 0; it < 2; ++it) {
      const int c = tid + it * 256;   // 512 16B chunks per 128x64 tile
      const int r = c >> 2;           // tile row
      const int s = c & 3;            // LDS slot within row
      const int kc = ((s - (r >> 1)) & 3) << 4;  // XOR-swizzled source chunk
      gl2lds16(xq  + (size_t)(m0 + r) * K + (k0 + kc), sA  + c * 16);
      gl2lds16(wgq + (size_t)(n0 + r) * K + (k0 + kc), sBg + c * 16);
      gl2lds16(wuq + (size_t)(n0 + r) * K + (k0 + kc), sBu + c * 16);
    }
    __syncthreads();

    i32x4 af[4];
#pragma unroll
    for (int i = 0; i < 4; ++i) {
      const int ar = wm * 64 + i * 16 + l16;
      af[i] = *(const i32x4*)(sA + ar * BK + (((quad + (ar >> 1)) & 3) << 4));
    }
#pragma unroll
    for (int j = 0; j < 4; ++j) {
      const int br = wn * 64 + j * 16 + l16;
      const int bo = br * BK + (((quad + (br >> 1)) & 3) << 4);
      i32x4 bg = *(const i32x4*)(sBg + bo);
      i32x4 bu = *(const i32x4*)(sBu + bo);
#pragma unroll
      for (int i = 0; i < 4; ++i) {
        accg[i][j] = __builtin_amdgcn_mfma_i32_16x16x64_i8(af[i], bg, accg[i][j], 0, 0, 0);
        accu[i][j] = __builtin_amdgcn_mfma_i32_16x16x64_i8(af[i], bu, accu[i][j], 0, 0, 0);
      }
    }
    __syncthreads();
  }

  float sg[4], su[4];
#pragma unroll
  for (int j = 0; j < 4; ++j) {
    const int col = n0 + wn * 64 + j * 16 + l16;
    sg[j] = swg[col];
    su[j] = swu[col];
  }
#pragma unroll
  for (int i = 0; i < 4; ++i) {
#pragma unroll
    for (int r = 0; r < 4; ++r) {
      const int row = m0 + wm * 64 + i * 16 + quad * 4 + r;
      const float s_x = sx[row];
      float rmax = 0.0f;
#pragma unroll
      for (int j = 0; j < 4; ++j) {
        const int col = n0 + wn * 64 + j * 16 + l16;
        const float g = (float)accg[i][j][r] * s_x * sg[j];
        const float u = (float)accu[i][j][r] * s_x * su[j];
        const float hv = (g / (1.0f + expf(-g))) * u;  // silu(g)*u
        hbuf[(size_t)row * N + col] = hv;
        rmax = fmaxf(rmax, fabsf(hv));
      }
      // reduce |h| max across the 16 lanes holding this row's columns
#pragma unroll
      for (int off = 8; off > 0; off >>= 1)
        rmax = fmaxf(rmax, __shfl_xor(rmax, off, 64));
      if (l16 == 0)
        atomicMax(hmax + row, __float_as_int(rmax));  // nonneg f32: int-mono
    }
  }
}

// Down-projection GEMM: out = (hq @ Wd^T) * sh[m] * swd[n]
// 128x256 tile, per-wave 64x128 (acc[4][8] = 128 VGPR), m-major raster.
__global__ __launch_bounds__(256, 2) void gemm2_kernel(
    const int8_t* __restrict__ hq, const int8_t* __restrict__ wdq,
    const float* __restrict__ sh, const float* __restrict__ swd,
    float* __restrict__ out, int M, int N, int K) {
  __shared__ __align__(16) int8_t sA[BM * BK];    // 8 KB
  __shared__ __align__(16) int8_t sB[BN2 * BK];   // 16 KB

  const int tid = threadIdx.x;
  const int lane = tid & 63;
  const int quad = lane >> 4;
  const int l16 = lane & 15;
  const int wave = tid >> 6;
  const int wm = wave >> 1;   // 0..1: 64-row group
  const int wn = wave & 1;    // 0..1: 128-col group

  const int nwg = gridDim.x * gridDim.y;
  const int lid = xcd_swizzle(blockIdx.y * gridDim.x + blockIdx.x, nwg);
  const int nm = gridDim.y;                 // # of m-tiles (32)
  const int m0 = (lid % nm) * BM;
  const int n0 = (lid / nm) * BN2;

  i32x4 acc[4][8] = {};

  for (int k0 = 0; k0 < K; k0 += BK) {
#pragma unroll
    for (int it = 0; it < 2; ++it) {  // A tile: 512 chunks
      const int c = tid + it * 256;
      const int r = c >> 2;
      const int s = c & 3;
      const int kc = ((s - (r >> 1)) & 3) << 4;
      gl2lds16(hq + (size_t)(m0 + r) * K + (k0 + kc), sA + c * 16);
    }
#pragma unroll
    for (int it = 0; it < 4; ++it) {  // B tile: 1024 chunks (256 rows)
      const int c = tid + it * 256;
      const int r = c >> 2;
      const int s = c & 3;
      const int kc = ((s - (r >> 1)) & 3) << 4;
      gl2lds16(wdq + (size_t)(n0 + r) * K + (k0 + kc), sB + c * 16);
    }
    __syncthreads();

    i32x4 af[4];
#pragma unroll
    for (int i = 0; i < 4; ++i) {
      const int ar = wm * 64 + i * 16 + l16;
      af[i] = *(const i32x4*)(sA + ar * BK + (((quad + (ar >> 1)) & 3) << 4));
    }
#pragma unroll
    for (int j = 0; j < 8; ++j) {
      const int br = wn * 128 + j * 16 + l16;
      i32x4 bf = *(const i32x4*)(sB + br * BK + (((quad + (br >> 1)) & 3) << 4));
#pragma unroll
      for (int i = 0; i < 4; ++i)
        acc[i][j] = __builtin_amdgcn_mfma_i32_16x16x64_i8(af[i], bf, acc[i][j], 0, 0, 0);
    }
    __syncthreads();
  }

  float sn[8];
#pragma unroll
  for (int j = 0; j < 8; ++j) sn[j] = swd[n0 + wn * 128 + j * 16 + l16];
#pragma unroll
  for (int i = 0; i < 4; ++i) {
#pragma unroll
    for (int r = 0; r < 4; ++r) {
      const int row = m0 + wm * 64 + i * 16 + quad * 4 + r;
      const float s_m = sh[row];
#pragma unroll
      for (int j = 0; j < 8; ++j) {
        const int col = n0 + wn * 128 + j * 16 + l16;
        out[(size_t)row * N + col] = (float)acc[i][j][r] * s_m * sn[j];
      }
    }
  }
}

extern "C" void kernel_launch(void* const* d_in, const int* in_sizes, int n_in,
                              void* d_out, int out_size, void* d_ws, size_t ws_size,
                              hipStream_t stream) {
  const float* x  = (const float*)d_in[0];   // [2,2048,4096]
  const float* Wg = (const float*)d_in[1];   // [11008,4096]
  const float* Wu = (const float*)d_in[2];   // [11008,4096]
  const float* Wd = (const float*)d_in[3];   // [4096,11008]
  float* out = (float*)d_out;                // [2,2048,4096] f32

  const int M = 4096;   // B*S
  const int D = 4096;
  const int F = 11008;

  // workspace layout (~378 MB total), all offsets 16B-aligned
  uint8_t* ws = (uint8_t*)d_ws;
  size_t off = 0;
  int8_t* xq  = (int8_t*)(ws + off); off += (size_t)M * D;      // 16 MB
  int8_t* wgq = (int8_t*)(ws + off); off += (size_t)F * D;      // 45 MB
  int8_t* wuq = (int8_t*)(ws + off); off += (size_t)F * D;      // 45 MB
  int8_t* wdq = (int8_t*)(ws + off); off += (size_t)D * F;      // 45 MB
  int8_t* hq  = (int8_t*)(ws + off); off += (size_t)M * F;      // 45 MB
  float* hbuf = (float*)(ws + off);  off += (size_t)M * F * 4;  // 180 MB
  float* sx   = (float*)(ws + off);  off += (size_t)M * 4;
  float* swg  = (float*)(ws + off);  off += (size_t)F * 4;
  float* swu  = (float*)(ws + off);  off += (size_t)F * 4;
  float* swd  = (float*)(ws + off);  off += (size_t)D * 4;
  float* sh   = (float*)(ws + off);  off += (size_t)M * 4;
  int*   hmax = (int*)(ws + off);    off += (size_t)M * 4;

  hipLaunchKernelGGL(quant_all_kernel, dim3(M + F + F + D), dim3(256), 0,
                     stream, x, Wg, Wu, Wd, xq, wgq, wuq, wdq,
                     sx, swg, swu, swd, hmax);
  hipLaunchKernelGGL(gemm1_kernel, dim3(F / BN, M / BM), dim3(256), 0, stream,
                     xq, wgq, wuq, sx, swg, swu, hbuf, hmax, M, F, D);
  hipLaunchKernelGGL(quant_h_kernel, dim3(M), dim3(256), 0, stream,
                     hbuf, hq, sh, hmax, F);
  hipLaunchKernelGGL(gemm2_kernel, dim3(D / BN2, M / BM), dim3(256), 0, stream,
                     hq, wdq, sh, swd, out, M, D, F);
}